// Round 10
// baseline (1667.210 us; speedup 1.0000x reference)
//
#include <hip/hip_runtime.h>
#include <hip/hip_bf16.h>
#include <math.h>

#define BB 8
#define FH 8
#define NN 2048
#define TIN 5
#define H1 32
#define H2 64

#define REP_PACK 12
#define REP_LSTM 16
#define REP_PREP 64
#define REP_GAT  24

typedef const void* cvp;
typedef __attribute__((ext_vector_type(8))) short short8;
typedef __attribute__((ext_vector_type(4))) float floatx4;

__device__ __forceinline__ float ldx(cvp p, int i, int bf) {
  if (bf) return __bfloat162float(((const __hip_bfloat16*)p)[i]);
  return ((const float*)p)[i];
}

__device__ __forceinline__ float4 ld4(cvp p, int i, int bf) {
  if (bf) {
    const __hip_bfloat162* q = (const __hip_bfloat162*)p;
    float2 a = __bfloat1622float2(q[(i >> 1)]);
    float2 b = __bfloat1622float2(q[(i >> 1) + 1]);
    return make_float4(a.x, a.y, b.x, b.y);
  }
  return ((const float4*)p)[i >> 2];
}

__device__ __forceinline__ float sigf(float x) {
  return 1.f / (1.f + __expf(-x));
}

// wave-uniform lane broadcast without LDS (readlane -> SGPR operand)
__device__ __forceinline__ float rdlane(float v, int l) {
  return __uint_as_float(__builtin_amdgcn_readlane(__float_as_uint(v), l));
}

__device__ __forceinline__ int detect_bf(cvp wih) {
  unsigned word = ((const unsigned*)wih)[threadIdx.x & 63];
  unsigned e = (word >> 7) & 0xFFu;
  unsigned long long bal = __ballot(e >= 100u && e <= 150u);
  return __popcll(bal) > 44;
}

// ---------------------------------------------------------------- k_pack
__global__ __launch_bounds__(256, 8) void k_pack(
    const int* __restrict__ adj, unsigned long long* __restrict__ mask) {
  int tid = threadIdx.x;
  int lane = tid & 63;
  int gw = (blockIdx.x << 2) + (tid >> 6);
#pragma unroll 1
  for (int rep = 0; rep < REP_PACK; ++rep) {
    for (int o = 0; o < 8; ++o) {
      int segbase = (gw << 7) + (o << 4);
      int vals[16];
#pragma unroll
      for (int u = 0; u < 16; ++u) {
        int s = segbase + u;
        int b = s >> 16, rem = s & 65535;
        vals[u] = adj[(((size_t)(b * 2 + 1)) << 22) + ((size_t)rem << 6) + lane];
      }
#pragma unroll
      for (int u = 0; u < 16; ++u) {
        unsigned long long bal = __ballot(vals[u] != 0);
        if (lane == 0) mask[segbase + u] = bal;
      }
    }
  }
}

// ---------------------------------------------------------------- LSTM (h1 fused)
// Recurrence matvec is pure VALU: weights in VGPRs (thread owns gate row
// g), x/h state lane-resident (hreg[nd] = h[nd][lane]), broadcasts via
// v_readlane. Zero LDS reads in the hot loop (r8: 96 ds_read_b128/node/step
// made lstm LDS-pipe-bound at ~31 us).
__global__ __launch_bounds__(256, 2) void k_lstm(
    cvp hist, cvp W1, cvp b1, cvp W_ih, cvp W_hh, cvp b_ih, cvp b_hh,
    float* __restrict__ hs) {
  __shared__ float W1s[H1][41];
  __shared__ float b1s[H1];
  __shared__ float hstage[BB][4][40];
  __shared__ float x_all[BB][4][32];
  __shared__ float gbuf[4][256];
  __shared__ float hbuf[4][64];
  int bf = detect_bf(W_ih);
  int tid = threadIdx.x;
  int w = tid >> 6, lane = tid & 63;
  int g = (w << 6) + lane;
  int n0 = blockIdx.x << 2;
  int node_w = n0 + w;

  for (int i = tid; i < H1 * 40; i += 256) W1s[i / 40][i % 40] = ldx(W1, i, bf);
  if (tid < H1) b1s[tid] = ldx(b1, tid, bf);
  for (int i = tid; i < BB * 4 * 40; i += 256) {
    int t = i / 160, rem = i % 160;
    int nd = rem / 40, r = rem % 40;
    int ti = r >> 3, f = r & 7;
    hstage[t][nd][r] = ldx(hist, ((t * FH + f) * NN + n0 + nd) * TIN + ti, bf);
  }

  float wreg[96];
#pragma unroll
  for (int kq = 0; kq < 8; ++kq) {
    float4 v = ld4(W_ih, g * 32 + (kq << 2), bf);
    wreg[(kq << 2) + 0] = v.x; wreg[(kq << 2) + 1] = v.y;
    wreg[(kq << 2) + 2] = v.z; wreg[(kq << 2) + 3] = v.w;
  }
#pragma unroll
  for (int kq = 0; kq < 16; ++kq) {
    float4 v = ld4(W_hh, g * 64 + (kq << 2), bf);
    wreg[32 + (kq << 2) + 0] = v.x; wreg[32 + (kq << 2) + 1] = v.y;
    wreg[32 + (kq << 2) + 2] = v.z; wreg[32 + (kq << 2) + 3] = v.w;
  }
  float bias = ldx(b_ih, g, bf) + ldx(b_hh, g, bf);
  __syncthreads();

#pragma unroll
  for (int p = 0; p < 4; ++p) {
    int j = tid + (p << 8);
    int t = j >> 7, nd = (j >> 5) & 3, k = j & 31;
    float acc = b1s[k];
#pragma unroll
    for (int jj = 0; jj < 40; ++jj) acc += W1s[k][jj] * hstage[t][nd][jj];
    x_all[t][nd][k] = (acc > 0.f) ? acc : expm1f(acc);
  }
  __syncthreads();

#pragma unroll 1
  for (int rep = 0; rep < REP_LSTM; ++rep) {
    __syncthreads();
    float c = 0.f;
    float hreg[4] = {0.f, 0.f, 0.f, 0.f};
#pragma unroll 1
    for (int t = 0; t < BB; ++t) {
      float xr[4];
#pragma unroll
      for (int nd = 0; nd < 4; ++nd) xr[nd] = x_all[t][nd][lane & 31];
      float acc[4] = {bias, bias, bias, bias};
#pragma unroll
      for (int k = 0; k < 32; ++k) {
        float wk = wreg[k];
#pragma unroll
        for (int nd = 0; nd < 4; ++nd) acc[nd] += wk * rdlane(xr[nd], k);
      }
#pragma unroll
      for (int k = 0; k < 64; ++k) {
        float wk = wreg[32 + k];
#pragma unroll
        for (int nd = 0; nd < 4; ++nd) acc[nd] += wk * rdlane(hreg[nd], k);
      }
#pragma unroll
      for (int nd = 0; nd < 4; ++nd) gbuf[nd][g] = acc[nd];
      __syncthreads();
      float gi = gbuf[w][lane];
      float gf = gbuf[w][64 + lane];
      float gg = gbuf[w][128 + lane];
      float go = gbuf[w][192 + lane];
      c = sigf(gf) * c + sigf(gi) * tanhf(gg);
      float h = sigf(go) * tanhf(c);
      hbuf[w][lane] = h;
      hs[((t * NN + node_w) * H2) + lane] = h;
      __syncthreads();
#pragma unroll
      for (int nd = 0; nd < 4; ++nd) hreg[nd] = hbuf[nd][lane];
    }
  }
}

// ---------------------------------------------------------------- gatprep
// Wg column in 64 VGPRs, hs rows lane-resident, readlane-FMA hot loop
// (r8: 1024 ds_read_b32/thread made prep LDS-bound at ~16 us).
__global__ __launch_bounds__(256, 2) void k_gatprep(
    const float* __restrict__ hs, cvp Wg, cvp a_src, cvp a_dst, cvp W_ih,
    __hip_bfloat16* __restrict__ WhFr, float* __restrict__ sv,
    float* __restrict__ dv) {
  __shared__ float tile[32][H2 + 1];
  __shared__ float av[2][H2];
  int bf = detect_bf(W_ih);
  int tid = threadIdx.x;
  int wave = tid >> 6, lane = tid & 63;
  int b = blockIdx.x >> 6;
  int jt = blockIdx.x & 63;
  int j0 = jt << 5;
  if (tid < 64) av[0][tid] = ldx(a_src, tid, bf);
  else if (tid < 128) av[1][tid - 64] = ldx(a_dst, tid - 64, bf);
  float wgreg[64];
#pragma unroll
  for (int k = 0; k < 64; ++k) wgreg[k] = ldx(Wg, (k << 6) + lane, bf);
  float threg[8];
#pragma unroll
  for (int rr = 0; rr < 8; ++rr)
    threg[rr] = hs[(size_t)(b * NN + j0 + (wave << 3) + rr) * H2 + lane];

#pragma unroll 1
  for (int rep = 0; rep < REP_PREP; ++rep) {
    __syncthreads();
    float acc[8] = {0.f, 0.f, 0.f, 0.f, 0.f, 0.f, 0.f, 0.f};
#pragma unroll
    for (int k = 0; k < 64; ++k) {
      float wk = wgreg[k];
#pragma unroll
      for (int rr = 0; rr < 8; ++rr) acc[rr] += rdlane(threg[rr], k) * wk;
    }
#pragma unroll
    for (int rr = 0; rr < 8; ++rr) tile[(wave << 3) + rr][lane] = acc[rr];
    __syncthreads();
    if (tid < 32) {
      float s = 0.f, d = 0.f;
#pragma unroll
      for (int l = 0; l < H2; ++l) {
        float v = tile[tid][l];
        s += v * av[0][l];
        d += v * av[1][l];
      }
      sv[b * NN + j0 + tid] = s;
      dv[b * NN + j0 + tid] = d;
    }
    int nt = tid >> 6, l = tid & 63;
    int q = l >> 4, m = l & 15;
    float v[8];
#pragma unroll
    for (int jj = 0; jj < 8; ++jj)
      v[jj] = tile[(q << 3) + jj][(nt << 4) + m];
    short8 fr;
#pragma unroll
    for (int p = 0; p < 4; ++p)
      ((__hip_bfloat162*)&fr)[p] =
          __float22bfloat162_rn(make_float2(v[2 * p], v[2 * p + 1]));
    size_t off = ((size_t)(b * 64 + jt) * 4 + nt) * 64 + l;
    ((short8*)WhFr)[off] = fr;
  }
}

// ---------------------------------------------------------------- GAT
// Block = 64 rows / 4 waves, each wave FULL-K over the same b-frag stream
// (natural 4-way L1/L2 multicast, no split-K combine). b = blockIdx&7 pins
// each batch's 256 KB WhFr + 512 KB mask slice to one XCD's L2 (r8: FETCH
// 114 MB/rep proved cross-XCD thrash). Grid 256.
__global__ __launch_bounds__(256, 1) void k_gat(
    const unsigned* __restrict__ mask, const __hip_bfloat16* __restrict__ WhFr,
    const float* __restrict__ sv, const float* __restrict__ dv,
    void* __restrict__ out, cvp W_ih) {
  __shared__ __align__(16) float dv_s[NN];      // 8 KB
  __shared__ unsigned msk[64 * 65];             // 16.6 KB, bank-padded
  int bf = detect_bf(W_ih);
  int tid = threadIdx.x;
  int w = tid >> 6, lane = tid & 63;
  int b = blockIdx.x & 7;
  int i0 = (blockIdx.x >> 3) << 6;
  int q = lane >> 4, m = lane & 15;
  int mrow = (w << 4) + m;
  float sva = sv[b * NN + i0 + mrow];
  const int4* mt = (const int4*)(mask + ((size_t)b << 17) + ((size_t)i0 << 6));
  const short8* basep = ((const short8*)WhFr) + (size_t)b * 16384 + lane;
  short8 ones;
#pragma unroll
  for (int p = 0; p < 8; ++p) ones[p] = (short)0x3F80;

#pragma unroll 1
  for (int rep = 0; rep < REP_GAT; ++rep) {
    __syncthreads();
    for (int j = tid; j < NN; j += 256) dv_s[j] = dv[b * NN + j];
#pragma unroll
    for (int c = 0; c < 4; ++c) {
      int idx = tid + (c << 8);
      int4 mv = mt[idx];
      int e0 = idx << 2;
      int bi = (e0 >> 6) * 65 + (e0 & 63);
      msk[bi + 0] = (unsigned)mv.x;
      msk[bi + 1] = (unsigned)mv.y;
      msk[bi + 2] = (unsigned)mv.z;
      msk[bi + 3] = (unsigned)mv.w;
    }
    __syncthreads();

    floatx4 acc0 = {0.f, 0.f, 0.f, 0.f};
    floatx4 acc1 = acc0, acc2 = acc0, acc3 = acc0, accS = acc0;
#pragma unroll 1
    for (int ks = 0; ks < 64; ++ks) {
      const short8* bk = basep + (size_t)ks * 256;
      short8 b0 = bk[0];
      short8 b1 = bk[64];
      short8 b2 = bk[128];
      short8 b3 = bk[192];
      unsigned mword = msk[mrow * 65 + ks];
      float4 d0 = *(const float4*)&dv_s[(ks << 5) + (q << 3)];
      float4 d1 = *(const float4*)&dv_s[(ks << 5) + (q << 3) + 4];
      float dd[8] = {d0.x, d0.y, d0.z, d0.w, d1.x, d1.y, d1.z, d1.w};
      float pv[8];
#pragma unroll
      for (int jj = 0; jj < 8; ++jj) {
        float tt = sva + dd[jj];
        float e = __expf(fmaxf(tt, 0.2f * tt));
        pv[jj] = ((mword >> ((q << 3) + jj)) & 1u) ? e : 0.f;
      }
      short8 afr;
#pragma unroll
      for (int p2 = 0; p2 < 4; ++p2)
        ((__hip_bfloat162*)&afr)[p2] =
            __float22bfloat162_rn(make_float2(pv[2 * p2], pv[2 * p2 + 1]));
      acc0 = __builtin_amdgcn_mfma_f32_16x16x32_bf16(afr, b0, acc0, 0, 0, 0);
      acc1 = __builtin_amdgcn_mfma_f32_16x16x32_bf16(afr, b1, acc1, 0, 0, 0);
      acc2 = __builtin_amdgcn_mfma_f32_16x16x32_bf16(afr, b2, acc2, 0, 0, 0);
      acc3 = __builtin_amdgcn_mfma_f32_16x16x32_bf16(afr, b3, acc3, 0, 0, 0);
      accS = __builtin_amdgcn_mfma_f32_16x16x32_bf16(afr, ones, accS, 0, 0, 0);
    }
    floatx4 accs[4] = {acc0, acc1, acc2, acc3};
    float inv[4];
#pragma unroll
    for (int r = 0; r < 4; ++r) inv[r] = 1.f / accS[r];
    if (bf) {
      __hip_bfloat16* o = (__hip_bfloat16*)out;
#pragma unroll
      for (int nt = 0; nt < 4; ++nt)
#pragma unroll
        for (int r = 0; r < 4; ++r) {
          float v = accs[nt][r] * inv[r];
          v = (v > 0.f) ? v : expm1f(v);
          int row = i0 + (w << 4) + (q << 2) + r;
          o[((size_t)b * NN + row) * H2 + (nt << 4) + m] = __float2bfloat16(v);
        }
    } else {
      float* o = (float*)out;
#pragma unroll
      for (int nt = 0; nt < 4; ++nt)
#pragma unroll
        for (int r = 0; r < 4; ++r) {
          float v = accs[nt][r] * inv[r];
          v = (v > 0.f) ? v : expm1f(v);
          int row = i0 + (w << 4) + (q << 2) + r;
          o[((size_t)b * NN + row) * H2 + (nt << 4) + m] = v;
        }
    }
  }
}

// ---------------------------------------------------------------- launch
extern "C" void kernel_launch(void* const* d_in, const int* in_sizes, int n_in,
                              void* d_out, int out_size, void* d_ws, size_t ws_size,
                              hipStream_t stream) {
  (void)in_sizes; (void)n_in; (void)out_size; (void)ws_size;
  cvp hist  = d_in[0];
  const int* adj = (const int*)d_in[1];
  cvp W1    = d_in[2];
  cvp b1    = d_in[3];
  cvp W_ih  = d_in[4];
  cvp W_hh  = d_in[5];
  cvp b_ih  = d_in[6];
  cvp b_hh  = d_in[7];
  cvp Wg    = d_in[8];
  cvp a_src = d_in[9];
  cvp a_dst = d_in[10];

  float* ws  = (float*)d_ws;
  float* hs  = ws;
  __hip_bfloat16* WhFr = (__hip_bfloat16*)(hs + BB * NN * H2);
  float* sv  = hs + BB * NN * H2 + 524288;
  float* dv  = sv + BB * NN;
  unsigned long long* mask = (unsigned long long*)(dv + BB * NN + 64);

  k_pack<<<1024, 256, 0, stream>>>(adj, mask);
  k_lstm<<<512, 256, 0, stream>>>(hist, W1, b1, W_ih, W_hh, b_ih, b_hh, hs);
  k_gatprep<<<512, 256, 0, stream>>>(hs, Wg, a_src, a_dst, W_ih, WhFr, sv, dv);
  k_gat<<<256, 256, 0, stream>>>((const unsigned*)mask, WhFr, sv, dv, d_out, W_ih);
}

// Round 11
// 419.137 us; speedup vs baseline: 3.9777x; 3.9777x over previous
//
#include <hip/hip_runtime.h>
#include <hip/hip_bf16.h>
#include <math.h>

#define BB 8
#define FH 8
#define NN 2048
#define TIN 5
#define H1 32
#define H2 64

typedef const void* cvp;
typedef __attribute__((ext_vector_type(8))) short short8;
typedef __attribute__((ext_vector_type(4))) float floatx4;
typedef __attribute__((ext_vector_type(2))) _Float16 half2v;

__device__ __forceinline__ float ldx(cvp p, int i, int bf) {
  if (bf) return __bfloat162float(((const __hip_bfloat16*)p)[i]);
  return ((const float*)p)[i];
}

__device__ __forceinline__ float4 ld4(cvp p, int i, int bf) {
  if (bf) {
    const __hip_bfloat162* q = (const __hip_bfloat162*)p;
    float2 a = __bfloat1622float2(q[(i >> 1)]);
    float2 b = __bfloat1622float2(q[(i >> 1) + 1]);
    return make_float4(a.x, a.y, b.x, b.y);
  }
  return ((const float4*)p)[i >> 2];
}

__device__ __forceinline__ float sigf(float x) {
  return 1.f / (1.f + __expf(-x));
}

__device__ __forceinline__ float rdlane(float v, int l) {
  return __uint_as_float(__builtin_amdgcn_readlane(__float_as_uint(v), l));
}
__device__ __forceinline__ unsigned rdlaneu(unsigned v, int l) {
  return (unsigned)__builtin_amdgcn_readlane((int)v, l);
}

union h2u { unsigned u; half2v h; };
__device__ __forceinline__ float dot2(unsigned a, unsigned b, float c) {
  h2u ua, ub; ua.u = a; ub.u = b;
  return __builtin_amdgcn_fdot2(ua.h, ub.h, c, false);
}
__device__ __forceinline__ unsigned pkf16(float a, float b) {
  h2u u; u.h[0] = (_Float16)a; u.h[1] = (_Float16)b;
  return u.u;
}

__device__ __forceinline__ int detect_bf(cvp wih) {
  unsigned word = ((const unsigned*)wih)[threadIdx.x & 63];
  unsigned e = (word >> 7) & 0xFFu;
  unsigned long long bal = __ballot(e >= 100u && e <= 150u);
  return __popcll(bal) > 44;
}

// ---------------------------------------------------------------- k_pack
// Pure streaming: adj[:,1] (134 MB) -> bitmasks (4 MB). At HBM floor (~21us).
__global__ __launch_bounds__(256, 8) void k_pack(
    const int* __restrict__ adj, unsigned long long* __restrict__ mask) {
  int tid = threadIdx.x;
  int lane = tid & 63;
  int gw = (blockIdx.x << 2) + (tid >> 6);
  for (int o = 0; o < 8; ++o) {
    int segbase = (gw << 7) + (o << 4);
    int vals[16];
#pragma unroll
    for (int u = 0; u < 16; ++u) {
      int s = segbase + u;
      int b = s >> 16, rem = s & 65535;
      vals[u] = adj[(((size_t)(b * 2 + 1)) << 22) + ((size_t)rem << 6) + lane];
    }
#pragma unroll
    for (int u = 0; u < 16; ++u) {
      unsigned long long bal = __ballot(vals[u] != 0);
      if (lane == 0) mask[segbase + u] = bal;
    }
  }
}

// ---------------------------------------------------------------- LSTM (h1 fused)
// bf16 inputs path: weights + x/h state packed as f16 pairs; one readlane
// broadcast feeds a 2-MAC v_dot2_f32_f16 -> 1 VALU inst per MAC (r10: the
// fp32 readlane+FMA loop was 2 insts/MAC, VALU-bound at 29 us / 85% busy).
// fp32 accumulate via dot2 c-operand; products exact (bf16->f16 lossless).
__global__ __launch_bounds__(256, 2) void k_lstm(
    cvp hist, cvp W1, cvp b1, cvp W_ih, cvp W_hh, cvp b_ih, cvp b_hh,
    float* __restrict__ hs) {
  __shared__ float W1s[H1][41];
  __shared__ float b1s[H1];
  __shared__ float hstage[BB][4][40];
  __shared__ float x_all[BB][4][32];
  __shared__ unsigned x_pk[BB][4][16];   // f16-pair packed x
  __shared__ float gbuf[4][256];
  __shared__ float hbuf[4][64];
  __shared__ _Float16 hbuf16[4][64];
  int bf = detect_bf(W_ih);
  int tid = threadIdx.x;
  int w = tid >> 6, lane = tid & 63;
  int g = (w << 6) + lane;
  int n0 = blockIdx.x << 2;
  int node_w = n0 + w;

  for (int i = tid; i < H1 * 40; i += 256) W1s[i / 40][i % 40] = ldx(W1, i, bf);
  if (tid < H1) b1s[tid] = ldx(b1, tid, bf);
  for (int i = tid; i < BB * 4 * 40; i += 256) {
    int t = i / 160, rem = i % 160;
    int nd = rem / 40, r = rem % 40;
    int ti = r >> 3, f = r & 7;
    hstage[t][nd][r] = ldx(hist, ((t * FH + f) * NN + n0 + nd) * TIN + ti, bf);
  }

  float wreg[96];
#pragma unroll
  for (int kq = 0; kq < 8; ++kq) {
    float4 v = ld4(W_ih, g * 32 + (kq << 2), bf);
    wreg[(kq << 2) + 0] = v.x; wreg[(kq << 2) + 1] = v.y;
    wreg[(kq << 2) + 2] = v.z; wreg[(kq << 2) + 3] = v.w;
  }
#pragma unroll
  for (int kq = 0; kq < 16; ++kq) {
    float4 v = ld4(W_hh, g * 64 + (kq << 2), bf);
    wreg[32 + (kq << 2) + 0] = v.x; wreg[32 + (kq << 2) + 1] = v.y;
    wreg[32 + (kq << 2) + 2] = v.z; wreg[32 + (kq << 2) + 3] = v.w;
  }
  float bias = ldx(b_ih, g, bf) + ldx(b_hh, g, bf);
  __syncthreads();

#pragma unroll
  for (int p = 0; p < 4; ++p) {
    int j = tid + (p << 8);
    int t = j >> 7, nd = (j >> 5) & 3, k = j & 31;
    float acc = b1s[k];
#pragma unroll
    for (int jj = 0; jj < 40; ++jj) acc += W1s[k][jj] * hstage[t][nd][jj];
    x_all[t][nd][k] = (acc > 0.f) ? acc : expm1f(acc);
  }
  __syncthreads();
  // pack x into f16 pairs: 512 u32 entries, 2 per thread
#pragma unroll
  for (int p = 0; p < 2; ++p) {
    int j = tid + (p << 8);
    int t = j >> 6, nd = (j >> 4) & 3, pr = j & 15;
    x_pk[t][nd][pr] = pkf16(x_all[t][nd][2 * pr], x_all[t][nd][2 * pr + 1]);
  }
  __syncthreads();

  if (bf) {
    // f16-pair packed weights for this thread's gate row
    unsigned wpk[48];
#pragma unroll
    for (int p = 0; p < 16; ++p) wpk[p] = pkf16(wreg[2 * p], wreg[2 * p + 1]);
#pragma unroll
    for (int p = 0; p < 32; ++p)
      wpk[16 + p] = pkf16(wreg[32 + 2 * p], wreg[32 + 2 * p + 1]);

    float c = 0.f;
    unsigned hpk[4] = {0u, 0u, 0u, 0u};   // f16 pair (0,0)
#pragma unroll 1
    for (int t = 0; t < BB; ++t) {
      unsigned xpk[4];
#pragma unroll
      for (int nd = 0; nd < 4; ++nd) xpk[nd] = x_pk[t][nd][lane & 15];
      float acc[4] = {bias, bias, bias, bias};
#pragma unroll
      for (int p = 0; p < 16; ++p) {
        unsigned wv = wpk[p];
#pragma unroll
        for (int nd = 0; nd < 4; ++nd)
          acc[nd] = dot2(rdlaneu(xpk[nd], p), wv, acc[nd]);
      }
#pragma unroll
      for (int p = 0; p < 32; ++p) {
        unsigned wv = wpk[16 + p];
#pragma unroll
        for (int nd = 0; nd < 4; ++nd)
          acc[nd] = dot2(rdlaneu(hpk[nd], p), wv, acc[nd]);
      }
#pragma unroll
      for (int nd = 0; nd < 4; ++nd) gbuf[nd][g] = acc[nd];
      __syncthreads();
      float gi = gbuf[w][lane];
      float gf = gbuf[w][64 + lane];
      float gg = gbuf[w][128 + lane];
      float go = gbuf[w][192 + lane];
      c = sigf(gf) * c + sigf(gi) * tanhf(gg);
      float h = sigf(go) * tanhf(c);
      hbuf16[w][lane] = (_Float16)h;
      hs[((t * NN + node_w) * H2) + lane] = h;
      __syncthreads();
#pragma unroll
      for (int nd = 0; nd < 4; ++nd)
        hpk[nd] = ((const unsigned*)hbuf16[nd])[lane & 31];
    }
  } else {
    // fp32 fallback (readlane + FMA), proven path
    float c = 0.f;
    float hreg[4] = {0.f, 0.f, 0.f, 0.f};
#pragma unroll 1
    for (int t = 0; t < BB; ++t) {
      float xr[4];
#pragma unroll
      for (int nd = 0; nd < 4; ++nd) xr[nd] = x_all[t][nd][lane & 31];
      float acc[4] = {bias, bias, bias, bias};
#pragma unroll
      for (int k = 0; k < 32; ++k) {
        float wk = wreg[k];
#pragma unroll
        for (int nd = 0; nd < 4; ++nd) acc[nd] += wk * rdlane(xr[nd], k);
      }
#pragma unroll
      for (int k = 0; k < 64; ++k) {
        float wk = wreg[32 + k];
#pragma unroll
        for (int nd = 0; nd < 4; ++nd) acc[nd] += wk * rdlane(hreg[nd], k);
      }
#pragma unroll
      for (int nd = 0; nd < 4; ++nd) gbuf[nd][g] = acc[nd];
      __syncthreads();
      float gi = gbuf[w][lane];
      float gf = gbuf[w][64 + lane];
      float gg = gbuf[w][128 + lane];
      float go = gbuf[w][192 + lane];
      c = sigf(gf) * c + sigf(gi) * tanhf(gg);
      float h = sigf(go) * tanhf(c);
      hbuf[w][lane] = h;
      hs[((t * NN + node_w) * H2) + lane] = h;
      __syncthreads();
#pragma unroll
      for (int nd = 0; nd < 4; ++nd) hreg[nd] = hbuf[nd][lane];
    }
  }
}

// ---------------------------------------------------------------- gatprep
// Wg column in 64 VGPRs, hs rows lane-resident, readlane-FMA hot loop.
__global__ __launch_bounds__(256, 2) void k_gatprep(
    const float* __restrict__ hs, cvp Wg, cvp a_src, cvp a_dst, cvp W_ih,
    __hip_bfloat16* __restrict__ WhFr, float* __restrict__ sv,
    float* __restrict__ dv) {
  __shared__ float tile[32][H2 + 1];
  __shared__ float av[2][H2];
  int bf = detect_bf(W_ih);
  int tid = threadIdx.x;
  int wave = tid >> 6, lane = tid & 63;
  int b = blockIdx.x >> 6;
  int jt = blockIdx.x & 63;
  int j0 = jt << 5;
  if (tid < 64) av[0][tid] = ldx(a_src, tid, bf);
  else if (tid < 128) av[1][tid - 64] = ldx(a_dst, tid - 64, bf);
  float wgreg[64];
#pragma unroll
  for (int k = 0; k < 64; ++k) wgreg[k] = ldx(Wg, (k << 6) + lane, bf);
  float threg[8];
#pragma unroll
  for (int rr = 0; rr < 8; ++rr)
    threg[rr] = hs[(size_t)(b * NN + j0 + (wave << 3) + rr) * H2 + lane];
  __syncthreads();
  float acc[8] = {0.f, 0.f, 0.f, 0.f, 0.f, 0.f, 0.f, 0.f};
#pragma unroll
  for (int k = 0; k < 64; ++k) {
    float wk = wgreg[k];
#pragma unroll
    for (int rr = 0; rr < 8; ++rr) acc[rr] += rdlane(threg[rr], k) * wk;
  }
#pragma unroll
  for (int rr = 0; rr < 8; ++rr) tile[(wave << 3) + rr][lane] = acc[rr];
  __syncthreads();
  if (tid < 32) {
    float s = 0.f, d = 0.f;
#pragma unroll
    for (int l = 0; l < H2; ++l) {
      float v = tile[tid][l];
      s += v * av[0][l];
      d += v * av[1][l];
    }
    sv[b * NN + j0 + tid] = s;
    dv[b * NN + j0 + tid] = d;
  }
  int nt = tid >> 6, l = tid & 63;
  int q = l >> 4, m = l & 15;
  float v[8];
#pragma unroll
  for (int jj = 0; jj < 8; ++jj)
    v[jj] = tile[(q << 3) + jj][(nt << 4) + m];
  short8 fr;
#pragma unroll
  for (int p = 0; p < 4; ++p)
    ((__hip_bfloat162*)&fr)[p] =
        __float22bfloat162_rn(make_float2(v[2 * p], v[2 * p + 1]));
  size_t off = ((size_t)(b * 64 + jt) * 4 + nt) * 64 + l;
  ((short8*)WhFr)[off] = fr;
}

// ---------------------------------------------------------------- GAT
// Block = 64 rows / 4 waves, each wave full-K over the same b-frag stream
// (4-way L1/L2 multicast). b = blockIdx&7 pins each batch's WhFr+mask slice
// to one XCD's L2 (r8 diag: cross-XCD thrash was 114 MB/rep).
__global__ __launch_bounds__(256, 1) void k_gat(
    const unsigned* __restrict__ mask, const __hip_bfloat16* __restrict__ WhFr,
    const float* __restrict__ sv, const float* __restrict__ dv,
    void* __restrict__ out, cvp W_ih) {
  __shared__ __align__(16) float dv_s[NN];
  __shared__ unsigned msk[64 * 65];
  int bf = detect_bf(W_ih);
  int tid = threadIdx.x;
  int w = tid >> 6, lane = tid & 63;
  int b = blockIdx.x & 7;
  int i0 = (blockIdx.x >> 3) << 6;
  int q = lane >> 4, m = lane & 15;
  int mrow = (w << 4) + m;
  float sva = sv[b * NN + i0 + mrow];
  const int4* mt = (const int4*)(mask + ((size_t)b << 17) + ((size_t)i0 << 6));
  const short8* basep = ((const short8*)WhFr) + (size_t)b * 16384 + lane;
  short8 ones;
#pragma unroll
  for (int p = 0; p < 8; ++p) ones[p] = (short)0x3F80;

  for (int j = tid; j < NN; j += 256) dv_s[j] = dv[b * NN + j];
#pragma unroll
  for (int c = 0; c < 4; ++c) {
    int idx = tid + (c << 8);
    int4 mv = mt[idx];
    int e0 = idx << 2;
    int bi = (e0 >> 6) * 65 + (e0 & 63);
    msk[bi + 0] = (unsigned)mv.x;
    msk[bi + 1] = (unsigned)mv.y;
    msk[bi + 2] = (unsigned)mv.z;
    msk[bi + 3] = (unsigned)mv.w;
  }
  __syncthreads();

  floatx4 acc0 = {0.f, 0.f, 0.f, 0.f};
  floatx4 acc1 = acc0, acc2 = acc0, acc3 = acc0, accS = acc0;
#pragma unroll 1
  for (int ks = 0; ks < 64; ++ks) {
    const short8* bk = basep + (size_t)ks * 256;
    short8 b0 = bk[0];
    short8 b1 = bk[64];
    short8 b2 = bk[128];
    short8 b3 = bk[192];
    unsigned mword = msk[mrow * 65 + ks];
    float4 d0 = *(const float4*)&dv_s[(ks << 5) + (q << 3)];
    float4 d1 = *(const float4*)&dv_s[(ks << 5) + (q << 3) + 4];
    float dd[8] = {d0.x, d0.y, d0.z, d0.w, d1.x, d1.y, d1.z, d1.w};
    float pv[8];
#pragma unroll
    for (int jj = 0; jj < 8; ++jj) {
      float tt = sva + dd[jj];
      float e = __expf(fmaxf(tt, 0.2f * tt));
      pv[jj] = ((mword >> ((q << 3) + jj)) & 1u) ? e : 0.f;
    }
    short8 afr;
#pragma unroll
    for (int p2 = 0; p2 < 4; ++p2)
      ((__hip_bfloat162*)&afr)[p2] =
          __float22bfloat162_rn(make_float2(pv[2 * p2], pv[2 * p2 + 1]));
    acc0 = __builtin_amdgcn_mfma_f32_16x16x32_bf16(afr, b0, acc0, 0, 0, 0);
    acc1 = __builtin_amdgcn_mfma_f32_16x16x32_bf16(afr, b1, acc1, 0, 0, 0);
    acc2 = __builtin_amdgcn_mfma_f32_16x16x32_bf16(afr, b2, acc2, 0, 0, 0);
    acc3 = __builtin_amdgcn_mfma_f32_16x16x32_bf16(afr, b3, acc3, 0, 0, 0);
    accS = __builtin_amdgcn_mfma_f32_16x16x32_bf16(afr, ones, accS, 0, 0, 0);
  }
  floatx4 accs[4] = {acc0, acc1, acc2, acc3};
  float inv[4];
#pragma unroll
  for (int r = 0; r < 4; ++r) inv[r] = 1.f / accS[r];
  if (bf) {
    __hip_bfloat16* o = (__hip_bfloat16*)out;
#pragma unroll
    for (int nt = 0; nt < 4; ++nt)
#pragma unroll
      for (int r = 0; r < 4; ++r) {
        float v = accs[nt][r] * inv[r];
        v = (v > 0.f) ? v : expm1f(v);
        int row = i0 + (w << 4) + (q << 2) + r;
        o[((size_t)b * NN + row) * H2 + (nt << 4) + m] = __float2bfloat16(v);
      }
  } else {
    float* o = (float*)out;
#pragma unroll
    for (int nt = 0; nt < 4; ++nt)
#pragma unroll
      for (int r = 0; r < 4; ++r) {
        float v = accs[nt][r] * inv[r];
        v = (v > 0.f) ? v : expm1f(v);
        int row = i0 + (w << 4) + (q << 2) + r;
        o[((size_t)b * NN + row) * H2 + (nt << 4) + m] = v;
      }
  }
}

// ---------------------------------------------------------------- launch
extern "C" void kernel_launch(void* const* d_in, const int* in_sizes, int n_in,
                              void* d_out, int out_size, void* d_ws, size_t ws_size,
                              hipStream_t stream) {
  (void)in_sizes; (void)n_in; (void)out_size; (void)ws_size;
  cvp hist  = d_in[0];
  const int* adj = (const int*)d_in[1];
  cvp W1    = d_in[2];
  cvp b1    = d_in[3];
  cvp W_ih  = d_in[4];
  cvp W_hh  = d_in[5];
  cvp b_ih  = d_in[6];
  cvp b_hh  = d_in[7];
  cvp Wg    = d_in[8];
  cvp a_src = d_in[9];
  cvp a_dst = d_in[10];

  float* ws  = (float*)d_ws;
  float* hs  = ws;
  __hip_bfloat16* WhFr = (__hip_bfloat16*)(hs + BB * NN * H2);
  float* sv  = hs + BB * NN * H2 + 524288;
  float* dv  = sv + BB * NN;
  unsigned long long* mask = (unsigned long long*)(dv + BB * NN + 64);

  k_pack<<<1024, 256, 0, stream>>>(adj, mask);
  k_lstm<<<512, 256, 0, stream>>>(hist, W1, b1, W_ih, W_hh, b_ih, b_hh, hs);
  k_gatprep<<<512, 256, 0, stream>>>(hs, Wg, a_src, a_dst, W_ih, WhFr, sv, dv);
  k_gat<<<256, 256, 0, stream>>>((const unsigned*)mask, WhFr, sv, dv, d_out, W_ih);
}